// Round 1
// baseline (31586.029 us; speedup 1.0000x reference)
//
#include <hip/hip_runtime.h>

#define NTHR 256
#define NB   16
#define NOSC 50
#define NPER 40
#define KTOT 2000           // NOSC*NPER
#define NSTEP 700
#define BATCH 4096
#define ASTR 2004           // act row stride (pad: breaks 2000-float bank aliasing, 16B aligned)
#define B1STR 36            // b1 row stride (16B-aligned, spreads banks)
#define HALF_PI 1.57079632679489662f
#define ACT_OFF ((size_t)NSTEP * BATCH * 4)

__device__ __forceinline__ float dot4(float4 a, float4 b, float acc) {
    acc = fmaf(a.x, b.x, acc);
    acc = fmaf(a.y, b.y, acc);
    acc = fmaf(a.z, b.z, acc);
    acc = fmaf(a.w, b.w, acc);
    return acc;
}

__global__ __launch_bounds__(NTHR, 1)
void net_main(const float* __restrict__ x,
              const float* __restrict__ fc1_w, const float* __restrict__ fc1_b,
              const float* __restrict__ fc2_w, const float* __restrict__ fc2_b,
              const float* __restrict__ fc3_w, const float* __restrict__ fc3_b,
              const float* __restrict__ fcd_w, const float* __restrict__ fcd_b,
              const float* __restrict__ enc,   const float* __restrict__ osc_bias,
              const float* __restrict__ dec,
              const float* __restrict__ fc4_w, const float* __restrict__ fc4_b,
              const float* __restrict__ fc5_w, const float* __restrict__ fc5_b,
              float* __restrict__ out)
{
    __shared__ __align__(16) float act[NB * ASTR];      // activities, fp32
    __shared__ __align__(16) float os [NOSC * NB * 2];  // oscillator states [o][b*2+d]
    __shared__ __align__(16) float b1s[NB * B1STR];     // fc4 output
    __shared__ __align__(16) float dir[NB * 2];         // direct term

    const int t  = threadIdx.x;
    const int b0 = blockIdx.x * NB;

    float* h  = act;            // [NB][128] (temp, pre-loop only)
    float* h2 = act + NB * 128; // [NB][128] (temp, pre-loop only)

    // ---------- precompute: fc1 ----------
    #pragma unroll
    for (int ii = 0; ii < (NB * 128) / NTHR; ++ii) {
        int task = t + ii * NTHR;
        int b = task >> 7, i = task & 127;
        float x0 = x[(b0 + b) * 2 + 0];
        float x1 = x[(b0 + b) * 2 + 1];
        float v = fmaf(x0, fc1_w[2 * i], fmaf(x1, fc1_w[2 * i + 1], fc1_b[i]));
        h[b * 128 + i] = fmaxf(v, 0.f);
    }
    __syncthreads();
    // ---------- precompute: fc2 -> h2, fcd -> direct ----------
    #pragma unroll
    for (int ii = 0; ii < (NB * 128) / NTHR; ++ii) {
        int task = t + ii * NTHR;
        int b = task >> 7, i = task & 127;
        float acc = fc2_b[i];
        #pragma unroll 4
        for (int k = 0; k < 128; k += 4)
            acc = dot4(*(const float4*)&fc2_w[i * 128 + k],
                       *(const float4*)&h[b * 128 + k], acc);
        h2[b * 128 + i] = fmaxf(acc, 0.f);
    }
    if (t < NB * 2) {
        int b = t >> 1, j = t & 1;
        float acc = fcd_b[j];
        #pragma unroll 4
        for (int k = 0; k < 128; k += 4)
            acc = dot4(*(const float4*)&fcd_w[j * 128 + k],
                       *(const float4*)&h[b * 128 + k], acc);
        dir[b * 2 + j] = acc;
    }
    __syncthreads();
    // ---------- precompute: fc3 -> o_states ----------
    #pragma unroll
    for (int ii = 0; ii < 7; ++ii) {
        int task = t + ii * NTHR;
        if (task < NOSC * NB * 2) {
            int o = task >> 5, r = task & 31, b = r >> 1, d = r & 1;
            int row = o * 2 + d;
            float acc = fc3_b[row];
            #pragma unroll 4
            for (int k = 0; k < 128; k += 4)
                acc = dot4(*(const float4*)&fc3_w[row * 128 + k],
                           *(const float4*)&h2[b * 128 + k], acc);
            os[o * 32 + r] = acc;
        }
    }
    // ---------- limb init (threads 0..15 own one batch row each) ----------
    float theta = 0.f, omega = 0.f, l1 = 0.f, l2 = 0.f, bs0 = 0.f, bs1 = 0.f;
    if (t < NB) {
        theta = x[(b0 + t) * 2 + 0];
        omega = 0.f;
        l1 = fmaf(-0.02f, theta, 0.1f);   // L0 - R_MOM*theta
        l2 = fmaf( 0.02f, theta, 0.1f);   // L0 + R_MOM*theta
        bs0 = dir[t * 2 + 0] + fc5_b[0];
        bs1 = dir[t * 2 + 1] + fc5_b[1];
    }
    __syncthreads();

    // phase-B invariants
    const int bb = t & 15, jj = t >> 4;
    const float* w0 = &fc4_w[(jj * 2 + 0) * KTOT];
    const float* w1 = &fc4_w[(jj * 2 + 1) * KTOT];
    const float* arow = &act[bb * ASTR];
    const float fb0 = fc4_b[jj * 2 + 0];
    const float fb1 = fc4_b[jj * 2 + 1];

    for (int s = 0; s < NSTEP; ++s) {
        // ---- phase A: a = relu(enc . o_states + bias) -> act (reads os, writes act)
        #pragma unroll
        for (int kk = 0; kk < 8; ++kk) {
            int k = t + kk * NTHR;
            if (k < KTOT) {
                int o = k / NPER;
                float e0 = enc[k * 2 + 0];
                float e1 = enc[k * 2 + 1];
                float bia = osc_bias[k];
                const float* osrow = &os[o * 32];
                #pragma unroll
                for (int b = 0; b < NB; ++b) {
                    float a = fmaf(e0, osrow[b * 2 + 0], fmaf(e1, osrow[b * 2 + 1], bia));
                    act[b * ASTR + k] = fmaxf(a, 0.f);
                }
            }
        }
        __syncthreads();

        // ---- deriv: o_states += DT * (dec . a)   (reads act, RMW os)
        #pragma unroll
        for (int ii = 0; ii < 7; ++ii) {
            int task = t + ii * NTHR;
            if (task < NOSC * NB * 2) {
                int o = task >> 5, r = task & 31, b = r >> 1, d = r & 1;
                const float* drow = &dec[(o * 2 + d) * NPER];
                const float* ar   = &act[b * ASTR + o * NPER];
                float acc0 = 0.f, acc1 = 0.f;
                #pragma unroll
                for (int p = 0; p < NPER; p += 8) {
                    acc0 = dot4(*(const float4*)&drow[p],     *(const float4*)&ar[p],     acc0);
                    acc1 = dot4(*(const float4*)&drow[p + 4], *(const float4*)&ar[p + 4], acc1);
                }
                os[o * 32 + r] += 0.001f * (acc0 + acc1);
            }
        }

        // ---- phase B: b1 = relu(act @ fc4_w.T + fc4_b)  (thread = (b, j-pair))
        {
            float a00 = 0.f, a01 = 0.f, a10 = 0.f, a11 = 0.f;
            #pragma unroll 2
            for (int k = 0; k < KTOT; k += 8) {
                float4 av0 = *(const float4*)&arow[k];
                float4 av1 = *(const float4*)&arow[k + 4];
                float4 wa0 = *(const float4*)&w0[k];
                float4 wa1 = *(const float4*)&w0[k + 4];
                float4 wb0 = *(const float4*)&w1[k];
                float4 wb1 = *(const float4*)&w1[k + 4];
                a00 = dot4(av0, wa0, a00);
                a01 = dot4(av1, wa1, a01);
                a10 = dot4(av0, wb0, a10);
                a11 = dot4(av1, wb1, a11);
            }
            b1s[bb * B1STR + jj * 2 + 0] = fmaxf((a00 + a01) + fb0, 0.f);
            b1s[bb * B1STR + jj * 2 + 1] = fmaxf((a10 + a11) + fb1, 0.f);
        }
        __syncthreads();

        // ---- phase C: fc5 + limb ODE + output stores (threads 0..15)
        if (t < NB) {
            float a0 = bs0, a1 = bs1;
            #pragma unroll
            for (int i = 0; i < 32; i += 4) {
                float4 bv = *(const float4*)&b1s[t * B1STR + i];
                a0 = dot4(bv, *(const float4*)&fc5_w[i],      a0);
                a1 = dot4(bv, *(const float4*)&fc5_w[32 + i], a1);
            }
            // limb_f on OLD l_state with current activation
            float f1v = fmaxf(a0, 0.f) * 50.f * fmaxf(l1 - 0.05f, 0.f);
            float f2v = fmaxf(a1, 0.f) * 50.f * fmaxf(l2 - 0.05f, 0.f);
            float domega = (0.02f * (f2v - f1v) - 0.01f * omega) / 0.001f;
            float dl1 = ((0.1f - 0.02f * theta) - l1) / 0.05f;
            float dl2 = ((0.1f + 0.02f * theta) - l2) / 0.05f;
            float pos = fmaf(0.001f, omega,  theta);
            float vel = fmaf(0.001f, domega, omega);
            l1 = fmaf(0.001f, dl1, l1);
            l2 = fmaf(0.001f, dl2, l2);
            bool inb = (pos > -HALF_PI) && (pos < HALF_PI);
            float posc = fminf(fmaxf(pos, -HALF_PI), HALF_PI);
            vel = inb ? vel : 0.f;
            theta = posc;
            omega = vel;
            float4 lo; lo.x = posc; lo.y = vel; lo.z = l1; lo.w = l2;
            *(float4*)&out[((size_t)s * BATCH + (b0 + t)) * 4] = lo;
            float2 ao; ao.x = a0; ao.y = a1;
            *(float2*)&out[ACT_OFF + ((size_t)s * BATCH + (b0 + t)) * 2] = ao;
        }
        __syncthreads();
    }
}

extern "C" void kernel_launch(void* const* d_in, const int* in_sizes, int n_in,
                              void* d_out, int out_size, void* d_ws, size_t ws_size,
                              hipStream_t stream) {
    (void)in_sizes; (void)n_in; (void)d_ws; (void)ws_size; (void)out_size;
    const float* x_     = (const float*)d_in[0];
    const float* fc1_w  = (const float*)d_in[1];
    const float* fc1_b  = (const float*)d_in[2];
    const float* fc2_w  = (const float*)d_in[3];
    const float* fc2_b  = (const float*)d_in[4];
    const float* fc3_w  = (const float*)d_in[5];
    const float* fc3_b  = (const float*)d_in[6];
    const float* fcd_w  = (const float*)d_in[7];
    const float* fcd_b  = (const float*)d_in[8];
    const float* enc    = (const float*)d_in[9];
    const float* oscb   = (const float*)d_in[10];
    const float* dec    = (const float*)d_in[11];
    const float* fc4_w  = (const float*)d_in[12];
    const float* fc4_b  = (const float*)d_in[13];
    const float* fc5_w  = (const float*)d_in[14];
    const float* fc5_b  = (const float*)d_in[15];
    float* out = (float*)d_out;

    hipLaunchKernelGGL(net_main, dim3(BATCH / NB), dim3(NTHR), 0, stream,
                       x_, fc1_w, fc1_b, fc2_w, fc2_b, fc3_w, fc3_b,
                       fcd_w, fcd_b, enc, oscb, dec, fc4_w, fc4_b,
                       fc5_w, fc5_b, out);
}

// Round 2
// 11386.667 us; speedup vs baseline: 2.7739x; 2.7739x over previous
//
#include <hip/hip_runtime.h>

#define NTHR 512
#define NB   8
#define NOSC 50
#define NPER 40
#define KTOT 2000
#define NSTEP 700
#define BATCH 4096
#define ASTR 2008           // act row stride in f16 elems (4016 B, 16B-aligned, banks 12b%32 distinct)
#define B1STR 36
#define HALF_PI 1.57079632679489662f
#define ACT_OFF ((size_t)NSTEP * BATCH * 4)

typedef _Float16 h2_t __attribute__((ext_vector_type(2)));

__device__ _Float16 g_w4[32 * KTOT];    // fc4_w in f16
__device__ _Float16 g_dec[100 * NPER];  // dec in f16

__device__ __forceinline__ float fdot2f(float a_bits, float b_bits, float acc) {
    h2_t a = __builtin_bit_cast(h2_t, a_bits);
    h2_t b = __builtin_bit_cast(h2_t, b_bits);
#if __has_builtin(__builtin_amdgcn_fdot2)
    return __builtin_amdgcn_fdot2(a, b, acc, false);
#else
    return fmaf((float)a[0], (float)b[0], fmaf((float)a[1], (float)b[1], acc));
#endif
}

__device__ __forceinline__ float dot4(float4 a, float4 b, float acc) {
    acc = fmaf(a.x, b.x, acc);
    acc = fmaf(a.y, b.y, acc);
    acc = fmaf(a.z, b.z, acc);
    acc = fmaf(a.w, b.w, acc);
    return acc;
}

__global__ void prep_f16(const float* __restrict__ fc4_w, const float* __restrict__ dec) {
    int tid = blockIdx.x * blockDim.x + threadIdx.x;
    if (tid < 32 * KTOT) g_w4[tid] = (_Float16)fc4_w[tid];
    if (tid < 100 * NPER) g_dec[tid] = (_Float16)dec[tid];
}

__global__ __launch_bounds__(NTHR, 4)
void net_main(const float* __restrict__ x,
              const float* __restrict__ fc1_w, const float* __restrict__ fc1_b,
              const float* __restrict__ fc2_w, const float* __restrict__ fc2_b,
              const float* __restrict__ fc3_w, const float* __restrict__ fc3_b,
              const float* __restrict__ fcd_w, const float* __restrict__ fcd_b,
              const float* __restrict__ enc,   const float* __restrict__ osc_bias,
              const float* __restrict__ fc4_b,
              const float* __restrict__ fc5_w, const float* __restrict__ fc5_b,
              float* __restrict__ out)
{
    __shared__ __align__(16) _Float16 act[NB * ASTR];   // activities, f16
    __shared__ __align__(16) float os [NOSC * NB * 2];  // oscillator states [o][b*2+d]
    __shared__ __align__(16) float part[2 * 32 * NB];   // phase-B partial sums
    __shared__ __align__(16) float b1s[NB * B1STR];
    __shared__ __align__(16) float dir[NB * 2];

    const int t  = threadIdx.x;
    const int b0 = blockIdx.x * NB;

    float* h  = (float*)act;        // [NB][128] temp, pre-loop only
    float* h2 = (float*)act + NB * 128;

    // ---------- precompute: fc1 ----------
    #pragma unroll
    for (int ii = 0; ii < 2; ++ii) {
        int task = t + ii * NTHR;   // 1024 tasks
        int b = task >> 7, i = task & 127;
        float x0 = x[(b0 + b) * 2 + 0];
        float x1 = x[(b0 + b) * 2 + 1];
        float v = fmaf(x0, fc1_w[2 * i], fmaf(x1, fc1_w[2 * i + 1], fc1_b[i]));
        h[b * 128 + i] = fmaxf(v, 0.f);
    }
    __syncthreads();
    // ---------- precompute: fc2 -> h2, fcd -> dir ----------
    #pragma unroll
    for (int ii = 0; ii < 2; ++ii) {
        int task = t + ii * NTHR;
        int b = task >> 7, i = task & 127;
        float acc = fc2_b[i];
        #pragma unroll 4
        for (int k = 0; k < 128; k += 4)
            acc = dot4(*(const float4*)&fc2_w[i * 128 + k],
                       *(const float4*)&h[b * 128 + k], acc);
        h2[b * 128 + i] = fmaxf(acc, 0.f);
    }
    if (t < NB * 2) {
        int b = t >> 1, j = t & 1;
        float acc = fcd_b[j];
        #pragma unroll 4
        for (int k = 0; k < 128; k += 4)
            acc = dot4(*(const float4*)&fcd_w[j * 128 + k],
                       *(const float4*)&h[b * 128 + k], acc);
        dir[b * 2 + j] = acc;
    }
    __syncthreads();
    // ---------- precompute: fc3 -> o_states ----------
    #pragma unroll
    for (int ii = 0; ii < 2; ++ii) {
        int task = t + ii * NTHR;
        if (task < NOSC * NB * 2) {  // 800 tasks
            int o = task >> 4, r = task & 15, b = r >> 1, d = r & 1;
            int row = o * 2 + d;
            float acc = fc3_b[row];
            #pragma unroll 4
            for (int k = 0; k < 128; k += 4)
                acc = dot4(*(const float4*)&fc3_w[row * 128 + k],
                           *(const float4*)&h2[b * 128 + k], acc);
            os[o * 16 + r] = acc;
        }
    }
    // ---------- limb init (threads 0..7) ----------
    float theta = 0.f, omega = 0.f, l1 = 0.f, l2 = 0.f, bs0 = 0.f, bs1 = 0.f;
    if (t < NB) {
        theta = x[(b0 + t) * 2 + 0];
        omega = 0.f;
        l1 = fmaf(-0.02f, theta, 0.1f);
        l2 = fmaf( 0.02f, theta, 0.1f);
    }
    __syncthreads();
    if (t < NB) {
        bs0 = dir[t * 2 + 0] + fc5_b[0];
        bs1 = dir[t * 2 + 1] + fc5_b[1];
    }

    // phase-B invariants: t = b(3) | j(5) | kc(1)
    const int bb = t & 7;
    const int jj = (t >> 3) & 31;
    const int kc = t >> 8;                      // 0 or 1
    const _Float16* arow = &act[bb * ASTR + kc * 1000];
    const _Float16* wrow = &g_w4[jj * KTOT + kc * 1000];

    for (int s = 0; s < NSTEP; ++s) {
        // ---- phase A: act = relu(enc . os + bias), f16 pack of 2 k per thread
        #pragma unroll
        for (int pp = 0; pp < 2; ++pp) {
            int p = t + pp * NTHR;              // k-pair index, 1000 total
            if (p < 1000) {
                int o = p / 20;                 // 20 pairs per oscillator
                float4 e  = *(const float4*)&enc[4 * p];      // e0a,e1a,e0b,e1b
                float2 bi = *(const float2*)&osc_bias[2 * p];
                const float* osrow = &os[o * 16];
                #pragma unroll
                for (int b = 0; b < NB; ++b) {
                    float a0 = fmaf(e.x, osrow[b * 2 + 0], fmaf(e.y, osrow[b * 2 + 1], bi.x));
                    float a1 = fmaf(e.z, osrow[b * 2 + 0], fmaf(e.w, osrow[b * 2 + 1], bi.y));
                    h2_t v;
                    v[0] = (_Float16)fmaxf(a0, 0.f);
                    v[1] = (_Float16)fmaxf(a1, 0.f);
                    *(h2_t*)&act[b * ASTR + 2 * p] = v;
                }
            }
        }
        __syncthreads();

        // ---- deriv: os += DT * (dec . a)
        #pragma unroll
        for (int ii = 0; ii < 2; ++ii) {
            int task = t + ii * NTHR;
            if (task < NOSC * NB * 2) {         // 800 tasks
                int o = task >> 4, r = task & 15, b = r >> 1, d = r & 1;
                const _Float16* dr = &g_dec[(o * 2 + d) * NPER];
                const _Float16* ar = &act[b * ASTR + o * NPER];
                float a0 = 0.f, a1 = 0.f, a2 = 0.f, a3 = 0.f;
                #pragma unroll
                for (int p = 0; p < NPER; p += 8) {
                    float4 af = *(const float4*)&ar[p];
                    float4 df = *(const float4*)&dr[p];
                    a0 = fdot2f(af.x, df.x, a0);
                    a1 = fdot2f(af.y, df.y, a1);
                    a2 = fdot2f(af.z, df.z, a2);
                    a3 = fdot2f(af.w, df.w, a3);
                }
                os[o * 16 + r] += 0.001f * ((a0 + a1) + (a2 + a3));
            }
        }

        // ---- phase B: partial b1 = act @ fc4_w.T over this thread's K-half
        {
            float a0 = 0.f, a1 = 0.f, a2 = 0.f, a3 = 0.f;
            #pragma unroll 5
            for (int k = 0; k < 1000; k += 8) {
                float4 af = *(const float4*)&arow[k];   // LDS, 8 f16
                float4 wf = *(const float4*)&wrow[k];   // global (L2-hot), 8 f16
                a0 = fdot2f(af.x, wf.x, a0);
                a1 = fdot2f(af.y, wf.y, a1);
                a2 = fdot2f(af.z, wf.z, a2);
                a3 = fdot2f(af.w, wf.w, a3);
            }
            part[kc * 256 + jj * 8 + bb] = (a0 + a1) + (a2 + a3);
        }
        __syncthreads();

        // ---- reduce K-halves -> b1
        if (t < 256) {
            int j = t >> 3, b = t & 7;
            float v = part[t] + part[256 + t] + fc4_b[j];
            b1s[b * B1STR + j] = fmaxf(v, 0.f);
        }
        __syncthreads();

        // ---- phase C: fc5 + limb ODE + stores (threads 0..7)
        if (t < NB) {
            float a0 = bs0, a1 = bs1;
            #pragma unroll
            for (int i = 0; i < 32; i += 4) {
                float4 bv = *(const float4*)&b1s[t * B1STR + i];
                a0 = dot4(bv, *(const float4*)&fc5_w[i],      a0);
                a1 = dot4(bv, *(const float4*)&fc5_w[32 + i], a1);
            }
            float f1v = fmaxf(a0, 0.f) * 50.f * fmaxf(l1 - 0.05f, 0.f);
            float f2v = fmaxf(a1, 0.f) * 50.f * fmaxf(l2 - 0.05f, 0.f);
            float domega = (0.02f * (f2v - f1v) - 0.01f * omega) / 0.001f;
            float dl1 = ((0.1f - 0.02f * theta) - l1) / 0.05f;
            float dl2 = ((0.1f + 0.02f * theta) - l2) / 0.05f;
            float pos = fmaf(0.001f, omega,  theta);
            float vel = fmaf(0.001f, domega, omega);
            l1 = fmaf(0.001f, dl1, l1);
            l2 = fmaf(0.001f, dl2, l2);
            bool inb = (pos > -HALF_PI) && (pos < HALF_PI);
            float posc = fminf(fmaxf(pos, -HALF_PI), HALF_PI);
            vel = inb ? vel : 0.f;
            theta = posc;
            omega = vel;
            float4 lo; lo.x = posc; lo.y = vel; lo.z = l1; lo.w = l2;
            *(float4*)&out[((size_t)s * BATCH + (b0 + t)) * 4] = lo;
            float2 ao; ao.x = a0; ao.y = a1;
            *(float2*)&out[ACT_OFF + ((size_t)s * BATCH + (b0 + t)) * 2] = ao;
        }
        __syncthreads();
    }
}

extern "C" void kernel_launch(void* const* d_in, const int* in_sizes, int n_in,
                              void* d_out, int out_size, void* d_ws, size_t ws_size,
                              hipStream_t stream) {
    (void)in_sizes; (void)n_in; (void)d_ws; (void)ws_size; (void)out_size;
    const float* x_     = (const float*)d_in[0];
    const float* fc1_w  = (const float*)d_in[1];
    const float* fc1_b  = (const float*)d_in[2];
    const float* fc2_w  = (const float*)d_in[3];
    const float* fc2_b  = (const float*)d_in[4];
    const float* fc3_w  = (const float*)d_in[5];
    const float* fc3_b  = (const float*)d_in[6];
    const float* fcd_w  = (const float*)d_in[7];
    const float* fcd_b  = (const float*)d_in[8];
    const float* enc    = (const float*)d_in[9];
    const float* oscb   = (const float*)d_in[10];
    const float* dec    = (const float*)d_in[11];
    const float* fc4_w  = (const float*)d_in[12];
    const float* fc4_b  = (const float*)d_in[13];
    const float* fc5_w  = (const float*)d_in[14];
    const float* fc5_b  = (const float*)d_in[15];
    float* out = (float*)d_out;

    hipLaunchKernelGGL(prep_f16, dim3((32 * KTOT + 255) / 256), dim3(256), 0, stream,
                       fc4_w, dec);
    hipLaunchKernelGGL(net_main, dim3(BATCH / NB), dim3(NTHR), 0, stream,
                       x_, fc1_w, fc1_b, fc2_w, fc2_b, fc3_w, fc3_b,
                       fcd_w, fcd_b, enc, oscb, fc4_b,
                       fc5_w, fc5_b, out);
}